// Round 1
// baseline (173.561 us; speedup 1.0000x reference)
//
#include <hip/hip_runtime.h>
#include <math.h>

#define BB 32
#define II 512
#define OO 512
#define NN 16

// One block per output column o. 512 threads; each thread handles 16
// (i,n) tuples (j = tid + 512*t), loops b=0..31 with 32 register
// accumulators. x staged in LDS in natural (b-major) layout: inner read
// xs[b*II+i] is a 16-lane broadcast across 4 banks -> conflict-free.
__global__ __launch_bounds__(512, 2)
void kat_kernel(const float* __restrict__ x,
                const float* __restrict__ mx_train,
                const float* __restrict__ scale,
                const float* __restrict__ sigma,
                const float* __restrict__ alpha,
                const float* __restrict__ w,
                const float* __restrict__ mx_start,
                float* __restrict__ out)
{
    __shared__ float xs[BB * II];   // 64 KB
    __shared__ float red[8][BB];    // 1 KB

    const int o   = blockIdx.x;
    const int tid = threadIdx.x;

    // stage x (coalesced global read, linear LDS write)
    for (int k = tid; k < BB * II; k += 512) xs[k] = x[k];
    __syncthreads();

    float acc[BB];
#pragma unroll
    for (int b = 0; b < BB; ++b) acc[b] = 0.0f;

    for (int t = 0; t < 16; ++t) {
        const int j  = tid + 512 * t;       // tuple index in [0, 8192)
        const int i  = j >> 4;
        const int n  = j & 15;
        const int io = i * OO + o;
        const int ion = io * NN + n;

        const float sg     = fabsf(sigma[ion]) + 1e-8f;
        const float c1     = 1.0f / sg;                       // amortized over 32 b
        const float center = fabsf(scale[io]) * mx_start[n] + mx_train[io];
        const float c0     = -center * c1;
        const float a2     = alpha[ion] * 0.7071067811865476f;
        const float wv     = w[ion];

#pragma unroll
        for (int b = 0; b < BB; ++b) {
            const float xv = xs[b * II + i];        // broadcast LDS read
            const float z  = fmaf(xv, c1, c0);      // (x - center) / sg
            const float u  = a2 * z;                // alpha*z/sqrt(2)
            const float e  = __expf(-z * z);
            const float g  = fmaf(e, erff(u), e);   // e * (1 + erf(u))
            acc[b] = fmaf(g, wv, acc[b]);
        }
    }

    // ---- reduction: per-wave shuffle, then cross-wave via LDS ----
    const int lane = tid & 63;
    const int wid  = tid >> 6;
#pragma unroll
    for (int b = 0; b < BB; ++b) {
        float v = acc[b];
        v += __shfl_xor(v, 1);
        v += __shfl_xor(v, 2);
        v += __shfl_xor(v, 4);
        v += __shfl_xor(v, 8);
        v += __shfl_xor(v, 16);
        v += __shfl_xor(v, 32);
        if (lane == 0) red[wid][b] = v;
    }
    __syncthreads();

    if (tid < BB) {
        float s = 0.0f;
#pragma unroll
        for (int wv2 = 0; wv2 < 8; ++wv2) s += red[wv2][tid];
        out[tid * OO + o] = s;   // out[b, o]
    }
}

extern "C" void kernel_launch(void* const* d_in, const int* in_sizes, int n_in,
                              void* d_out, int out_size, void* d_ws, size_t ws_size,
                              hipStream_t stream)
{
    const float* x        = (const float*)d_in[0];
    const float* mx_train = (const float*)d_in[1];
    const float* scale    = (const float*)d_in[2];
    const float* sigma    = (const float*)d_in[3];
    const float* alpha    = (const float*)d_in[4];
    const float* w        = (const float*)d_in[5];
    const float* mx_start = (const float*)d_in[6];
    float* out            = (float*)d_out;

    kat_kernel<<<OO, 512, 0, stream>>>(x, mx_train, scale, sigma, alpha, w,
                                       mx_start, out);
}

// Round 2
// 71.567 us; speedup vs baseline: 2.4252x; 2.4252x over previous
//
#include <hip/hip_runtime.h>
#include <math.h>

#define BB 32
#define II 512
#define OO 512
#define NN 16

#if __has_builtin(__builtin_amdgcn_exp2f)
#define EXP2F(x) __builtin_amdgcn_exp2f(x)
#else
#define EXP2F(x) exp2f(x)
#endif
#if __has_builtin(__builtin_amdgcn_rcpf)
#define RCPF(x) __builtin_amdgcn_rcpf(x)
#else
#define RCPF(x) (1.0f / (x))
#endif

// Constants:
//  S      = sqrt(log2(e))  — z is pre-scaled by S so exp(-z^2) = exp2(-zs^2)
//  K_A2N  = INV_SQRT2 / S  — u = alpha*z/sqrt(2) = (alpha*K_A2N)*zs
//  A&S 7.1.25: erf(x) = 1 - (a1 t + a2 t^2 + a3 t^3) e^{-x^2}, t=1/(1+p x), |err|<=2.5e-5
#define KS      1.2011224087f
#define K_A2N   0.5887050112f
#define LOG2E   1.4426950408f
#define ERF_P   0.47047f
#define ERF_A1  0.3480242f
#define ERF_A2  (-0.0958798f)
#define ERF_A3  0.7478556f

// One block per output column o. 512 threads; each thread handles 16
// (i,n) tuples (j = tid + 512*t), loops b=0..31 with 32 register
// accumulators. x staged in LDS in natural (b-major) layout: inner read
// xs[b*II+i] is a 16-lane broadcast across 4 banks -> conflict-free.
__global__ __launch_bounds__(512, 2)
void kat_kernel(const float* __restrict__ x,
                const float* __restrict__ mx_train,
                const float* __restrict__ scale,
                const float* __restrict__ sigma,
                const float* __restrict__ alpha,
                const float* __restrict__ w,
                const float* __restrict__ mx_start,
                float* __restrict__ out)
{
    __shared__ float xs[BB * II];   // 64 KB
    __shared__ float red[8][BB];    // 1 KB

    const int o   = blockIdx.x;
    const int tid = threadIdx.x;

    // stage x (coalesced global read, linear LDS write)
    for (int k = tid; k < BB * II; k += 512) xs[k] = x[k];
    __syncthreads();

    float acc[BB];
#pragma unroll
    for (int b = 0; b < BB; ++b) acc[b] = 0.0f;

    for (int t = 0; t < 16; ++t) {
        const int j   = tid + 512 * t;       // tuple index in [0, 8192)
        const int i   = j >> 4;
        const int n   = j & 15;
        const int io  = i * OO + o;
        const int ion = io * NN + n;

        // per-tuple constants (amortized over 32 b)
        const float sg     = fabsf(sigma[ion]) + 1e-8f;
        const float c1     = RCPF(sg);
        const float center = fmaf(fabsf(scale[io]), mx_start[n], mx_train[io]);
        const float c1s    = c1 * KS;            // scaled slope: zs = z*sqrt(log2e)
        const float c0s    = -center * c1s;
        const float al     = alpha[ion];
        const float a2n    = al * K_A2N;         // u = a2n * zs  (natural units)
        const float a2sq   = (a2n * a2n) * LOG2E; // so a2sq*(-zs^2) = -u^2*log2e
        const float wv     = w[ion];

#pragma unroll
        for (int b = 0; b < BB; ++b) {
            const float xv = xs[b * II + i];         // broadcast LDS read
            const float zs = fmaf(xv, c1s, c0s);     // z * sqrt(log2e)
            const float m  = -zs * zs;               // -z^2 * log2e
            const float e  = EXP2F(m);               // exp(-z^2)
            const float u  = a2n * zs;               // alpha*z/sqrt(2)
            const float e2 = EXP2F(a2sq * m);        // exp(-u^2)
            // A&S 7.1.25, branchless, valid for all |u|
            const float d    = fmaf(ERF_P, fabsf(u), 1.0f);
            const float rt   = RCPF(d);              // t
            float h = fmaf(ERF_A3, rt, ERF_A2);
            h = fmaf(h, rt, ERF_A1);                 // a1 + a2 t + a3 t^2
            const float pe   = rt * e2;              // t * exp(-u^2)
            const float erfa = fmaf(-h, pe, 1.0f);   // erf(|u|)
            const float erfu = __builtin_copysignf(erfa, u);
            const float g    = fmaf(e, erfu, e);     // exp(-z^2)*(1+erf(u))
            acc[b] = fmaf(g, wv, acc[b]);
        }
    }

    // ---- reduction: per-wave shuffle, then cross-wave via LDS ----
    const int lane = tid & 63;
    const int wid  = tid >> 6;
#pragma unroll
    for (int b = 0; b < BB; ++b) {
        float v = acc[b];
        v += __shfl_xor(v, 1);
        v += __shfl_xor(v, 2);
        v += __shfl_xor(v, 4);
        v += __shfl_xor(v, 8);
        v += __shfl_xor(v, 16);
        v += __shfl_xor(v, 32);
        if (lane == 0) red[wid][b] = v;
    }
    __syncthreads();

    if (tid < BB) {
        float s = 0.0f;
#pragma unroll
        for (int wv2 = 0; wv2 < 8; ++wv2) s += red[wv2][tid];
        out[tid * OO + o] = s;   // out[b, o]
    }
}

extern "C" void kernel_launch(void* const* d_in, const int* in_sizes, int n_in,
                              void* d_out, int out_size, void* d_ws, size_t ws_size,
                              hipStream_t stream)
{
    const float* x        = (const float*)d_in[0];
    const float* mx_train = (const float*)d_in[1];
    const float* scale    = (const float*)d_in[2];
    const float* sigma    = (const float*)d_in[3];
    const float* alpha    = (const float*)d_in[4];
    const float* w        = (const float*)d_in[5];
    const float* mx_start = (const float*)d_in[6];
    float* out            = (float*)d_out;

    kat_kernel<<<OO, 512, 0, stream>>>(x, mx_train, scale, sigma, alpha, w,
                                       mx_start, out);
}